// Round 5
// baseline (670.184 us; speedup 1.0000x reference)
//
#include <hip/hip_runtime.h>
#include <hip/hip_bf16.h>
#include <math.h>

// Problem constants
constexpr int Bc = 4;
constexpr int Sc = 2048;
constexpr int Dc = 512;
constexpr int Hc = 8;
constexpr int DHc = 64;
constexpr int Lc = 4;
constexpr int DFFc = 2048;
constexpr int Tc = Bc * Sc;   // 8192 tokens
constexpr int QKVW = 3 * Dc;  // 1536

typedef __attribute__((ext_vector_type(8))) short short8;
typedef __attribute__((ext_vector_type(4))) float f32x4;

static __device__ __forceinline__ float u16tof(unsigned int u) {
  return __uint_as_float(u << 16);
}
static __device__ __forceinline__ unsigned short ftobf(float f) {
  __hip_bfloat16 h = __float2bfloat16(f);
  return *reinterpret_cast<unsigned short*>(&h);
}
static __device__ __forceinline__ void gload_lds16(const void* g, void* l) {
  __builtin_amdgcn_global_load_lds(
      (const __attribute__((address_space(1))) void*)g,
      (__attribute__((address_space(3))) void*)l, 16, 0, 0);
}

// LDS chunk-swizzle helpers for attention (16B-chunk XOR, conflict-free b128)
static __device__ __forceinline__ int swzK(int row, int col) {  // width 64
  return row * 64 + ((((col >> 3) ^ (row & 7)) << 3) | (col & 7));
}
static __device__ __forceinline__ int swzW(int row, int col) {  // width 192
  return row * 192 + ((((col >> 3) ^ (row & 7)) << 3) | (col & 7));
}

// ---------------------------------------------------------------------------
// fp32 -> bf16 conversion (weights, once per launch)
// ---------------------------------------------------------------------------
__global__ __launch_bounds__(256) void k_f2bf(const float* __restrict__ in,
                                              unsigned short* __restrict__ out,
                                              int n) {
  int i = blockIdx.x * 256 + threadIdx.x;
  if (i < n) out[i] = ftobf(in[i]);
}

// ---------------------------------------------------------------------------
// Embed: h = x @ W_in^T + b_in + pos ; also bf16 copy
// ---------------------------------------------------------------------------
__global__ __launch_bounds__(256) void k_embed(const float* __restrict__ x,
                                               const float* __restrict__ W_in,
                                               const float* __restrict__ b_in,
                                               const float* __restrict__ pos,
                                               float* __restrict__ h,
                                               unsigned short* __restrict__ hb) {
  int idx = blockIdx.x * 256 + threadIdx.x;
  int t = idx >> 9;
  int d = idx & 511;
  int s = t & (Sc - 1);
  float v = x[t * 2 + 0] * W_in[d * 2 + 0] + x[t * 2 + 1] * W_in[d * 2 + 1] +
            b_in[d] + pos[(size_t)s * Dc + d];
  h[idx] = v;
  hb[idx] = ftobf(v);
}

// ---------------------------------------------------------------------------
// MFMA bf16 GEMM, depth-3 pipelined (counted vmcnt, raw barriers),
// chunk-swizzled LDS, XCD block swizzle.
//   C[m,n] = sum_k A[m,k]*W[n,k] + bias[n]  (+ epilogue)
//   MODE 0: +bias ; MODE 1: +bias+res ; MODE 2: +bias, exact GELU
//   OUTBF: 1 -> bf16 out, 0 -> fp32 out ; KK: compile-time K (512/2048)
// 128x128 tile, BK=32, 256 threads (4 waves, 2x2), mfma_f32_16x16x32_bf16.
// 4 LDS buffers; tile s+3 staged at step s; vmcnt never drained to 0 in-loop.
// ---------------------------------------------------------------------------
template <int MODE, int OUTBF, int KK>
__global__ __launch_bounds__(256) void k_mgemm(const unsigned short* __restrict__ A,
                                               const unsigned short* __restrict__ W,
                                               const float* __restrict__ bias,
                                               const float* __restrict__ res,
                                               void* __restrict__ Cout,
                                               int M, int N) {
  constexpr int NSTEP = KK / 32;
  __shared__ short As[4][512 * 8];
  __shared__ short Bs[4][512 * 8];
  const int tid = threadIdx.x;
  const int lane = tid & 63;
  const int wid = tid >> 6;
  const int wm = wid >> 1;  // 0..1
  const int wn = wid & 1;   // 0..1

  // XCD-aware block swizzle (all grids used here have nwg % 8 == 0)
  const int nwg = gridDim.x * gridDim.y;
  const int bid = blockIdx.y * gridDim.x + blockIdx.x;
  const int swz = (bid & 7) * (nwg >> 3) + (bid >> 3);
  const int m0 = (swz / gridDim.x) * 128;
  const int n0 = (swz % gridDim.x) * 128;

  // staging: invert chunk-permutation p -> (row, ch) for this thread's 2 slots
  int r0S, c0S, r1S, c1S;
  {
    int p = tid;
    int rp = p >> 3, q = (p & 7) ^ (rp & 7);
    r0S = (rp << 1) | (q >> 2);
    c0S = q & 3;
    p = tid + 256;
    rp = p >> 3;
    q = (p & 7) ^ (rp & 7);
    r1S = (rp << 1) | (q >> 2);
    c1S = q & 3;
  }
  const unsigned short* a0p = A + (size_t)(m0 + r0S) * KK + c0S * 8;
  const unsigned short* a1p = A + (size_t)(m0 + r1S) * KK + c1S * 8;
  const unsigned short* b0p = W + (size_t)(n0 + r0S) * KK + c0S * 8;
  const unsigned short* b1p = W + (size_t)(n0 + r1S) * KK + c1S * 8;
  const int d0 = (tid & ~63) * 8;          // linear LDS dest (shorts), issue 0
  const int d1 = ((tid + 256) & ~63) * 8;  // issue 1

  f32x4 acc[4][4] = {};
  const int lr = lane & 15;
  const int chr = lane >> 4;  // fragment k-block == chunk index

  // prologue: stage tiles 0..2 (12 loads in flight)
#pragma unroll
  for (int t = 0; t < 3; ++t) {
    const int ko = t * 32;
    gload_lds16(a0p + ko, &As[t][d0]);
    gload_lds16(a1p + ko, &As[t][d1]);
    gload_lds16(b0p + ko, &Bs[t][d0]);
    gload_lds16(b1p + ko, &Bs[t][d1]);
  }

#pragma unroll 4
  for (int s = 0; s < NSTEP; ++s) {
    // wait for tile s only (leave tiles s+1, s+2 in flight), then sync
    if (s + 3 <= NSTEP)
      asm volatile("s_waitcnt vmcnt(8)" ::: "memory");
    else if (s + 2 <= NSTEP)
      asm volatile("s_waitcnt vmcnt(4)" ::: "memory");
    else
      asm volatile("s_waitcnt vmcnt(0)" ::: "memory");
    __builtin_amdgcn_s_barrier();
    __builtin_amdgcn_sched_barrier(0);

    // stage tile s+3 into buf (s+3)&3  (overwrites tile s-1's buffer: safe,
    // all waves' step s-1 ds_reads completed before the barrier above)
    if (s + 3 < NSTEP) {
      const int ko = (s + 3) * 32;
      const int nb = (s + 3) & 3;
      gload_lds16(a0p + ko, &As[nb][d0]);
      gload_lds16(a1p + ko, &As[nb][d1]);
      gload_lds16(b0p + ko, &Bs[nb][d0]);
      gload_lds16(b1p + ko, &Bs[nb][d1]);
    }

    const int buf = s & 3;
    short8 af[4], bfr[4];
#pragma unroll
    for (int mi = 0; mi < 4; ++mi) {
      int row = wm * 64 + mi * 16 + lr;
      int rp = row >> 1;
      int p = rp * 8 + (((((row & 1) << 2) | chr)) ^ (rp & 7));
      af[mi] = *(const short8*)&As[buf][p * 8];
    }
#pragma unroll
    for (int ni = 0; ni < 4; ++ni) {
      int row = wn * 64 + ni * 16 + lr;
      int rp = row >> 1;
      int p = rp * 8 + (((((row & 1) << 2) | chr)) ^ (rp & 7));
      bfr[ni] = *(const short8*)&Bs[buf][p * 8];
    }
    __builtin_amdgcn_s_setprio(1);
#pragma unroll
    for (int mi = 0; mi < 4; ++mi)
#pragma unroll
      for (int ni = 0; ni < 4; ++ni)
        acc[mi][ni] = __builtin_amdgcn_mfma_f32_16x16x32_bf16(
            af[mi], bfr[ni], acc[mi][ni], 0, 0, 0);
    __builtin_amdgcn_s_setprio(0);
  }

  // epilogue: C/D layout col = lane&15, row = (lane>>4)*4 + j
  const int cj = lane & 15;
  const int rj = (lane >> 4) * 4;
#pragma unroll
  for (int mi = 0; mi < 4; ++mi) {
#pragma unroll
    for (int ni = 0; ni < 4; ++ni) {
      int n = n0 + wn * 64 + ni * 16 + cj;
      float bn = bias[n];
#pragma unroll
      for (int j = 0; j < 4; ++j) {
        int m = m0 + wm * 64 + mi * 16 + rj + j;
        float v = acc[mi][ni][j] + bn;
        if (MODE == 1) v += res[(size_t)m * N + n];
        if (MODE == 2) v = 0.5f * v * (1.0f + erff(v * 0.70710678118654752f));
        if (OUTBF)
          ((unsigned short*)Cout)[(size_t)m * N + n] = ftobf(v);
        else
          ((float*)Cout)[(size_t)m * N + n] = v;
      }
    }
  }
}

// ---------------------------------------------------------------------------
// Windowed causal attention, MFMA. qkv bf16 [T][1536].
// Block: 64 queries of one (b,h); 4 waves x 16 queries.
// Swapped QK^T (A=K,B=Q^T) -> lane-local softmax; P->LDS; PV (A=P,B=V^T).
// ---------------------------------------------------------------------------
__global__ __launch_bounds__(256) void k_attn(const unsigned short* __restrict__ qkv,
                                              unsigned short* __restrict__ o) {
  __shared__ unsigned short Ks[192 * 64];
  __shared__ unsigned short Vt[64 * 192];
  __shared__ unsigned short Ps[64 * 192];

  const int tid = threadIdx.x;
  const int lane = tid & 63;
  const int w = tid >> 6;
  const int idx = blockIdx.x;
  const int qb = idx & 31;
  const int hh = (idx >> 5) & 7;
  const int b = idx >> 8;
  const int q0 = qb * 64;
  const int kstart = max(0, q0 - 128);
  const int nk = q0 + 64 - kstart;  // 64 (qb==0) or 192

  for (int c = tid; c < nk * 8; c += 256) {
    int j = c >> 3, ch = c & 7;
    short8 kv = *(const short8*)&qkv[(size_t)(b * Sc + kstart + j) * QKVW + Dc + hh * DHc + ch * 8];
    *(short8*)&Ks[swzK(j, ch * 8)] = kv;
  }
  for (int c = tid; c < (nk >> 1) * 8; c += 256) {
    int jp = c >> 3, ch = c & 7;
    int j = jp * 2;
    const unsigned short* base =
        &qkv[(size_t)(b * Sc + kstart + j) * QKVW + 2 * Dc + hh * DHc + ch * 8];
    short8 v0 = *(const short8*)base;
    short8 v1 = *(const short8*)(base + QKVW);
#pragma unroll
    for (int i = 0; i < 8; ++i) {
      unsigned int pk = (unsigned short)v0[i] | ((unsigned int)(unsigned short)v1[i] << 16);
      *(unsigned int*)&Vt[swzW(ch * 8 + i, j)] = pk;
    }
  }
  if (nk < 192) {
    for (int c = tid; c < 64 * 64; c += 256) {
      int d = c >> 6, jo = c & 63;
      *(unsigned int*)&Vt[swzW(d, 64 + jo * 2)] = 0;
    }
  }

  const int qg = q0 + w * 16 + (lane & 15);
  const int kg8 = (lane >> 4) * 8;
  const unsigned short* qp = &qkv[(size_t)(b * Sc + qg) * QKVW + hh * DHc + kg8];
  short8 bq0 = *(const short8*)qp;
  short8 bq1 = *(const short8*)(qp + 32);
  __syncthreads();

  const int jb = max(0, q0 + w * 16 - 128) - kstart;

  f32x4 sacc[9];
#pragma unroll
  for (int t = 0; t < 9; ++t) {
    int key = jb + t * 16 + (lane & 15);
    short8 a0 = *(const short8*)&Ks[swzK(key, kg8)];
    short8 a1 = *(const short8*)&Ks[swzK(key, 32 + kg8)];
    f32x4 z = {0.f, 0.f, 0.f, 0.f};
    z = __builtin_amdgcn_mfma_f32_16x16x32_bf16(a0, bq0, z, 0, 0, 0);
    sacc[t] = __builtin_amdgcn_mfma_f32_16x16x32_bf16(a1, bq1, z, 0, 0, 0);
  }

  const int rj = (lane >> 4) * 4;
  float mx = -1e30f;
#pragma unroll
  for (int t = 0; t < 9; ++t) {
#pragma unroll
    for (int j = 0; j < 4; ++j) {
      int kglob = kstart + jb + t * 16 + rj + j;
      bool valid = (kglob <= qg) && (kglob + 128 >= qg);
      float s = valid ? sacc[t][j] * 0.125f : -1e30f;
      sacc[t][j] = s;
      mx = fmaxf(mx, s);
    }
  }
  mx = fmaxf(mx, __shfl_xor(mx, 16));
  mx = fmaxf(mx, __shfl_xor(mx, 32));
  float sum = 0.f;
#pragma unroll
  for (int t = 0; t < 9; ++t)
#pragma unroll
    for (int j = 0; j < 4; ++j) {
      float e = __expf(sacc[t][j] - mx);
      sacc[t][j] = e;
      sum += e;
    }
  sum += __shfl_xor(sum, 16);
  sum += __shfl_xor(sum, 32);
  const float inv = 1.0f / sum;

  const int prow = w * 16 + (lane & 15);
#pragma unroll
  for (int t = 0; t < 9; ++t) {
    int c0 = jb + t * 16 + rj;
    unsigned int p0 = ftobf(sacc[t][0] * inv) |
                      ((unsigned int)ftobf(sacc[t][1] * inv) << 16);
    unsigned int p1 = ftobf(sacc[t][2] * inv) |
                      ((unsigned int)ftobf(sacc[t][3] * inv) << 16);
    *(unsigned int*)&Ps[swzW(prow, c0)] = p0;
    *(unsigned int*)&Ps[swzW(prow, c0 + 2)] = p1;
  }
  {
    int g2 = (lane >> 4) * 2;
    for (int col = g2; col < jb; col += 8)
      *(unsigned int*)&Ps[swzW(prow, col)] = 0;
    for (int col = jb + 144 + g2; col < 192; col += 8)
      *(unsigned int*)&Ps[swzW(prow, col)] = 0;
  }
  f32x4 oacc[4] = {};
#pragma unroll
  for (int kb = 0; kb < 6; ++kb) {
    short8 pa = *(const short8*)&Ps[swzW(prow, kb * 32 + kg8)];
#pragma unroll
    for (int dt = 0; dt < 4; ++dt) {
      short8 vb = *(const short8*)&Vt[swzW(dt * 16 + (lane & 15), kb * 32 + kg8)];
      oacc[dt] = __builtin_amdgcn_mfma_f32_16x16x32_bf16(pa, vb, oacc[dt], 0, 0, 0);
    }
  }
  const int cj = lane & 15;
#pragma unroll
  for (int j = 0; j < 4; ++j)
#pragma unroll
    for (int dt = 0; dt < 4; ++dt)
      o[(size_t)(b * Sc + q0 + w * 16 + rj + j) * Dc + hh * DHc + dt * 16 + cj] =
          ftobf(oacc[dt][j]);
}

// ---------------------------------------------------------------------------
// LayerNorm over D=512, one wave per token; fp32 + bf16 outputs.
// ---------------------------------------------------------------------------
__global__ __launch_bounds__(256) void k_ln(const float* __restrict__ in,
                                            const float* __restrict__ g,
                                            const float* __restrict__ bta,
                                            float* __restrict__ out,
                                            unsigned short* __restrict__ outb) {
  const int wid = threadIdx.x >> 6;
  const int lane = threadIdx.x & 63;
  const int t = blockIdx.x * 4 + wid;
  const float* row = in + (size_t)t * Dc;
  float v[8];
  float sum = 0.0f, sq = 0.0f;
#pragma unroll
  for (int i = 0; i < 8; ++i) {
    float xv = row[lane + i * 64];
    v[i] = xv;
    sum += xv;
    sq += xv * xv;
  }
#pragma unroll
  for (int off = 32; off; off >>= 1) {
    sum += __shfl_xor(sum, off);
    sq += __shfl_xor(sq, off);
  }
  float m = sum * (1.0f / 512.0f);
  float var = sq * (1.0f / 512.0f) - m * m;
  float rstd = rsqrtf(var + 1e-5f);
#pragma unroll
  for (int i = 0; i < 8; ++i) {
    int d = lane + i * 64;
    float ov = (v[i] - m) * rstd * g[d] + bta[d];
    out[(size_t)t * Dc + d] = ov;
    outb[(size_t)t * Dc + d] = ftobf(ov);
  }
}

// ---------------------------------------------------------------------------
// Head (fp32): mu | clipped log_sigma
// ---------------------------------------------------------------------------
__global__ __launch_bounds__(256) void k_head(const float* __restrict__ h,
                                              const float* __restrict__ Wh,
                                              const float* __restrict__ bh,
                                              float* __restrict__ outp) {
  const int wid = threadIdx.x >> 6;
  const int lane = threadIdx.x & 63;
  const int t = blockIdx.x * 4 + wid;
  const float* row = h + (size_t)t * Dc;
  float a0 = 0, a1 = 0, a2 = 0, a3 = 0;
#pragma unroll
  for (int i = 0; i < 8; ++i) {
    int d = lane + i * 64;
    float xv = row[d];
    a0 += xv * Wh[0 * Dc + d];
    a1 += xv * Wh[1 * Dc + d];
    a2 += xv * Wh[2 * Dc + d];
    a3 += xv * Wh[3 * Dc + d];
  }
#pragma unroll
  for (int off = 32; off; off >>= 1) {
    a0 += __shfl_xor(a0, off);
    a1 += __shfl_xor(a1, off);
    a2 += __shfl_xor(a2, off);
    a3 += __shfl_xor(a3, off);
  }
  if (lane == 0) {
    outp[(size_t)t * 2 + 0] = a0 + bh[0];
    outp[(size_t)t * 2 + 1] = a1 + bh[1];
    outp[(size_t)Tc * 2 + (size_t)t * 2 + 0] = fminf(fmaxf(a2 + bh[2], -6.0f), 1.5f);
    outp[(size_t)Tc * 2 + (size_t)t * 2 + 1] = fminf(fmaxf(a3 + bh[3], -6.0f), 1.5f);
  }
}

// ---------------------------------------------------------------------------
extern "C" void kernel_launch(void* const* d_in, const int* in_sizes, int n_in,
                              void* d_out, int out_size, void* d_ws, size_t ws_size,
                              hipStream_t stream) {
  const float* x    = (const float*)d_in[0];
  const float* W_in = (const float*)d_in[1];
  const float* b_in = (const float*)d_in[2];
  const float* pos  = (const float*)d_in[3];
  const float* Wqkv = (const float*)d_in[4];
  const float* bqkv = (const float*)d_in[5];
  const float* Wo   = (const float*)d_in[6];
  const float* bo   = (const float*)d_in[7];
  const float* W1   = (const float*)d_in[8];
  const float* b1   = (const float*)d_in[9];
  const float* W2   = (const float*)d_in[10];
  const float* b2   = (const float*)d_in[11];
  const float* ln1g = (const float*)d_in[12];
  const float* ln1b = (const float*)d_in[13];
  const float* ln2g = (const float*)d_in[14];
  const float* ln2b = (const float*)d_in[15];
  const float* Wh   = (const float*)d_in[16];
  const float* bh   = (const float*)d_in[17];
  float* out = (float*)d_out;

  char* p = (char*)d_ws;
  float* h  = (float*)p;           p += (size_t)Tc * Dc * 4;
  float* t2 = (float*)p;           p += (size_t)Tc * Dc * 4;
  unsigned short* hb  = (unsigned short*)p; p += (size_t)Tc * Dc * 2;
  unsigned short* ob  = (unsigned short*)p; p += (size_t)Tc * Dc * 2;
  unsigned short* big = (unsigned short*)p; p += (size_t)Tc * DFFc * 2;
  unsigned short* wqb = (unsigned short*)p; p += (size_t)Lc * QKVW * Dc * 2;
  unsigned short* wob = (unsigned short*)p; p += (size_t)Lc * Dc * Dc * 2;
  unsigned short* w1b = (unsigned short*)p; p += (size_t)Lc * DFFc * Dc * 2;
  unsigned short* w2b = (unsigned short*)p; p += (size_t)Lc * Dc * DFFc * 2;

  k_f2bf<<<Lc * QKVW * Dc / 256, 256, 0, stream>>>(Wqkv, wqb, Lc * QKVW * Dc);
  k_f2bf<<<Lc * Dc * Dc / 256, 256, 0, stream>>>(Wo, wob, Lc * Dc * Dc);
  k_f2bf<<<Lc * DFFc * Dc / 256, 256, 0, stream>>>(W1, w1b, Lc * DFFc * Dc);
  k_f2bf<<<Lc * Dc * DFFc / 256, 256, 0, stream>>>(W2, w2b, Lc * Dc * DFFc);

  k_embed<<<(Tc * Dc) / 256, 256, 0, stream>>>(x, W_in, b_in, pos, h, hb);

  for (int l = 0; l < Lc; ++l) {
    const unsigned short* wq_l = wqb + (size_t)l * QKVW * Dc;
    const unsigned short* wo_l = wob + (size_t)l * Dc * Dc;
    const unsigned short* w1_l = w1b + (size_t)l * DFFc * Dc;
    const unsigned short* w2_l = w2b + (size_t)l * Dc * DFFc;

    k_mgemm<0, 1, Dc><<<dim3(QKVW / 128, Tc / 128), 256, 0, stream>>>(
        hb, wq_l, bqkv + (size_t)l * QKVW, nullptr, big, Tc, QKVW);

    k_attn<<<Bc * Hc * (Sc / 64), 256, 0, stream>>>(big, ob);

    k_mgemm<1, 0, Dc><<<dim3(Dc / 128, Tc / 128), 256, 0, stream>>>(
        ob, wo_l, bo + (size_t)l * Dc, h, t2, Tc, Dc);

    k_ln<<<Tc / 4, 256, 0, stream>>>(t2, ln1g + (size_t)l * Dc, ln1b + (size_t)l * Dc, h, hb);

    k_mgemm<2, 1, Dc><<<dim3(DFFc / 128, Tc / 128), 256, 0, stream>>>(
        hb, w1_l, b1 + (size_t)l * DFFc, nullptr, big, Tc, DFFc);

    k_mgemm<1, 0, DFFc><<<dim3(Dc / 128, Tc / 128), 256, 0, stream>>>(
        big, w2_l, b2 + (size_t)l * Dc, h, t2, Tc, Dc);

    k_ln<<<Tc / 4, 256, 0, stream>>>(t2, ln2g + (size_t)l * Dc, ln2b + (size_t)l * Dc, h, hb);
  }

  k_head<<<Tc / 4, 256, 0, stream>>>(h, Wh, bh, out);
}